// Round 1
// baseline (841.432 us; speedup 1.0000x reference)
//
#include <hip/hip_runtime.h>
#include <hip/hip_bf16.h>
#include <stdint.h>

#define NORI   197
#define FRAMES 8
#define NTOK   1576      // FRAMES*NORI
#define BATCH  8
#define NHEAD  12
#define CDIM   768
#define MG     204       // gathered tokens per batch
#define TOKENS 12608     // 64*197

// ---- static gather/mask helpers (frame lengths: 25,25,25,25,24,24,24,24) ----
__device__ __forceinline__ int gather_idx(int m) {
    if (m < 8) return m * NORI;
    int u = m - 8;
    int f, t;
    if (u < 100) { f = u / 25; t = u - f * 25; }
    else         { f = 4 + (u - 100) / 24; t = (u - 100) - (f - 4) * 24; }
    return f * NORI + 1 + f + 8 * t;
}
__device__ __forceinline__ int col_frame(int m) {  // m >= 8
    int u = m - 8;
    return (u < 100) ? (u / 25) : (4 + (u - 100) / 24);
}

__device__ __forceinline__ float readlane_f(float v, int l) {
    return __uint_as_float(__builtin_amdgcn_readlane(__float_as_uint(v), l));
}
__device__ __forceinline__ float wave_max(float v) {
#pragma unroll
    for (int off = 32; off > 0; off >>= 1) v = fmaxf(v, __shfl_xor(v, off, 64));
    return v;
}
__device__ __forceinline__ float wave_sum(float v) {
#pragma unroll
    for (int off = 32; off > 0; off >>= 1) v += __shfl_xor(v, off, 64);
    return v;
}

// ---- fp32 tiled GEMM: Y[r, c] = sum_k A[row(r), k] * W[Woff+c, k] (+bias) ----
// K fixed = 768. Tile 64x64, BK=32, 256 threads, 4x4 microtile.
__global__ __launch_bounds__(256) void gemm_k768(
    const float* __restrict__ A, const float* __restrict__ W,
    const float* __restrict__ bias, float* __restrict__ Y,
    int M, int Woff, int ldY, int gather)
{
    __shared__ float As[32][68];
    __shared__ float Bs[32][68];
    const int tid = threadIdx.x;
    const int r0 = blockIdx.x * 64;
    const int c0 = blockIdx.y * 64;
    const int tx = tid & 15, ty = tid >> 4;

    const int lrow = tid >> 2;          // 0..63
    const int kq   = (tid & 3) * 4;     // 0,4,8,12

    int ar = r0 + lrow;
    bool avalid = (ar < M);
    int asrc = 0;
    if (avalid) {
        if (gather) { int b = ar / MG; int m = ar - b * MG; asrc = b * NTOK + gather_idx(m); }
        else asrc = ar;
    }
    const float* Arow = A + (size_t)asrc * CDIM;
    const float* Wrow = W + (size_t)(Woff + c0 + lrow) * CDIM;

    float acc[4][4] = {};
    for (int kb = 0; kb < CDIM; kb += 32) {
        float4 a0 = avalid ? *(const float4*)(Arow + kb + kq)      : float4{0,0,0,0};
        float4 a1 = avalid ? *(const float4*)(Arow + kb + 16 + kq) : float4{0,0,0,0};
        float4 b0 = *(const float4*)(Wrow + kb + kq);
        float4 b1 = *(const float4*)(Wrow + kb + 16 + kq);
        __syncthreads();
        As[kq+0][lrow] = a0.x; As[kq+1][lrow] = a0.y; As[kq+2][lrow] = a0.z; As[kq+3][lrow] = a0.w;
        As[kq+16][lrow] = a1.x; As[kq+17][lrow] = a1.y; As[kq+18][lrow] = a1.z; As[kq+19][lrow] = a1.w;
        Bs[kq+0][lrow] = b0.x; Bs[kq+1][lrow] = b0.y; Bs[kq+2][lrow] = b0.z; Bs[kq+3][lrow] = b0.w;
        Bs[kq+16][lrow] = b1.x; Bs[kq+17][lrow] = b1.y; Bs[kq+18][lrow] = b1.z; Bs[kq+19][lrow] = b1.w;
        __syncthreads();
#pragma unroll
        for (int kk = 0; kk < 32; kk++) {
            float4 av = *(const float4*)&As[kk][ty * 4];
            float4 bv = *(const float4*)&Bs[kk][tx * 4];
            acc[0][0] += av.x * bv.x; acc[0][1] += av.x * bv.y; acc[0][2] += av.x * bv.z; acc[0][3] += av.x * bv.w;
            acc[1][0] += av.y * bv.x; acc[1][1] += av.y * bv.y; acc[1][2] += av.y * bv.z; acc[1][3] += av.y * bv.w;
            acc[2][0] += av.z * bv.x; acc[2][1] += av.z * bv.y; acc[2][2] += av.z * bv.z; acc[2][3] += av.z * bv.w;
            acc[3][0] += av.w * bv.x; acc[3][1] += av.w * bv.y; acc[3][2] += av.w * bv.z; acc[3][3] += av.w * bv.w;
        }
    }

    const int rbase = r0 + ty * 4;
    const int cbase = c0 + tx * 4;
    float4 bs = bias ? *(const float4*)&bias[cbase] : float4{0,0,0,0};
#pragma unroll
    for (int a = 0; a < 4; a++) {
        int r = rbase + a;
        if (r < M) {
            float4 o;
            o.x = acc[a][0] + bs.x; o.y = acc[a][1] + bs.y;
            o.z = acc[a][2] + bs.z; o.w = acc[a][3] + bs.w;
            *(float4*)&Y[(size_t)r * ldY + cbase] = o;
        }
    }
}

// ---- fused masked attention: per block = one (b,h), 64-row chunk ----
// Q: [12608,768] fp32, KV: [8*204,1536] fp32 (K ch 0..767 is at +0, V at +768)
// AO: [12608,768] fp32 (token-major, head channels interleaved)
__global__ __launch_bounds__(256) void attn_fused(
    const float* __restrict__ Q, const float* __restrict__ KV,
    float* __restrict__ AO)
{
    __shared__ __align__(16) __hip_bfloat16 KsT[64 * MG];   // [d][m]
    __shared__ __align__(16) __hip_bfloat16 Vs[MG * 64];    // [m][d]
    __shared__ __align__(16) __hip_bfloat16 Ps[4][MG * 8];  // [wave][m][r]

    const int tid = threadIdx.x;
    const int bh = blockIdx.x;
    const int b = bh & 7, h = bh >> 3;
    const int n0 = blockIdx.y * 64;

    // stage K (transposed, bf16) and V (bf16)
    for (int e = tid; e < MG * 64; e += 256) {
        int m = e >> 6, d = e & 63;
        const float* src = KV + (size_t)(b * MG + m) * 1536 + h * 64 + d;
        KsT[d * MG + m] = __float2bfloat16(src[0]);
        Vs[m * 64 + d]  = __float2bfloat16(src[768]);
    }
    __syncthreads();

    const int w = tid >> 6, lane = tid & 63;
    __hip_bfloat16* Psw = Ps[w];

    const int mc0 = lane, mc1 = lane + 64, mc2 = lane + 128, mc3 = lane + 192;
    const bool c3ok = (lane < 12);
    int cfr[4];
    cfr[0] = (mc0 < 8) ? -1 : col_frame(mc0);
    cfr[1] = col_frame(mc1);
    cfr[2] = col_frame(mc2);
    cfr[3] = c3ok ? col_frame(mc3) : -2;

    for (int it = 0; it < 2; it++) {
        int rb = n0 + it * 32 + w * 8;
        if (rb >= NTOK) break;
        int nvalid = min(8, NTOK - rb);

        float qreg[8];
#pragma unroll
        for (int r = 0; r < 8; r++) {
            int n = rb + ((r < nvalid) ? r : (nvalid - 1));
            qreg[r] = Q[(size_t)(b * NTOK + n) * CDIM + h * 64 + lane];
        }

        float acc[8][4] = {};
#pragma unroll 4
        for (int d = 0; d < 64; d++) {
            float k0 = __bfloat162float(KsT[d * MG + mc0]);
            float k1 = __bfloat162float(KsT[d * MG + mc1]);
            float k2 = __bfloat162float(KsT[d * MG + mc2]);
            float k3 = c3ok ? __bfloat162float(KsT[d * MG + mc3]) : 0.f;
#pragma unroll
            for (int r = 0; r < 8; r++) {
                float qv = readlane_f(qreg[r], d);
                acc[r][0] += qv * k0; acc[r][1] += qv * k1;
                acc[r][2] += qv * k2; acc[r][3] += qv * k3;
            }
        }

        // softmax per row (mask: cls or same-frame -> 1.0 else 0.8)
#pragma unroll
        for (int r = 0; r < 8; r++) {
            int n = rb + r;
            int rf = n / NORI;
            float s0 = acc[r][0] * 0.125f * ((cfr[0] < 0 || cfr[0] == rf) ? 1.f : 0.8f);
            float s1 = acc[r][1] * 0.125f * ((cfr[1] == rf) ? 1.f : 0.8f);
            float s2 = acc[r][2] * 0.125f * ((cfr[2] == rf) ? 1.f : 0.8f);
            float s3 = c3ok ? acc[r][3] * 0.125f * ((cfr[3] == rf) ? 1.f : 0.8f) : -1e30f;
            float mx = fmaxf(fmaxf(s0, s1), fmaxf(s2, s3));
            mx = wave_max(mx);
            float e0 = __expf(s0 - mx), e1 = __expf(s1 - mx), e2 = __expf(s2 - mx);
            float e3 = c3ok ? __expf(s3 - mx) : 0.f;
            float sum = wave_sum(e0 + e1 + e2 + e3);
            float inv = 1.f / sum;
            Psw[mc0 * 8 + r] = __float2bfloat16(e0 * inv);
            Psw[mc1 * 8 + r] = __float2bfloat16(e1 * inv);
            Psw[mc2 * 8 + r] = __float2bfloat16(e2 * inv);
            if (c3ok) Psw[mc3 * 8 + r] = __float2bfloat16(e3 * inv);
        }

        // PV: lane = d, loop over m
        float acc2[8] = {};
#pragma unroll 2
        for (int m = 0; m < MG; m++) {
            float vv = __bfloat162float(Vs[m * 64 + lane]);
            uint4 u = *(const uint4*)(Psw + m * 8);
            float p0 = __uint_as_float(u.x << 16), p1 = __uint_as_float(u.x & 0xffff0000u);
            float p2 = __uint_as_float(u.y << 16), p3 = __uint_as_float(u.y & 0xffff0000u);
            float p4 = __uint_as_float(u.z << 16), p5 = __uint_as_float(u.z & 0xffff0000u);
            float p6 = __uint_as_float(u.w << 16), p7 = __uint_as_float(u.w & 0xffff0000u);
            acc2[0] += p0 * vv; acc2[1] += p1 * vv; acc2[2] += p2 * vv; acc2[3] += p3 * vv;
            acc2[4] += p4 * vv; acc2[5] += p5 * vv; acc2[6] += p6 * vv; acc2[7] += p7 * vv;
        }
#pragma unroll
        for (int r = 0; r < 8; r++) {
            if (r < nvalid)
                AO[(size_t)(b * NTOK + rb + r) * CDIM + h * 64 + lane] = acc2[r];
        }
    }
}

extern "C" void kernel_launch(void* const* d_in, const int* in_sizes, int n_in,
                              void* d_out, int out_size, void* d_ws, size_t ws_size,
                              hipStream_t stream) {
    const float* x      = (const float*)d_in[0];
    const float* qkv_w  = (const float*)d_in[1];
    const float* proj_w = (const float*)d_in[2];
    const float* proj_b = (const float*)d_in[3];
    float* out = (float*)d_out;

    float* Qb  = (float*)d_ws;                            // 12608*768
    float* KVb = Qb + (size_t)TOKENS * CDIM;              // 1632*1536
    float* AOb = KVb + (size_t)(BATCH * MG) * 1536;       // 12608*768

    dim3 blk(256);
    // Q = x @ qkv_w[0:768].T
    gemm_k768<<<dim3(TOKENS / 64, CDIM / 64), blk, 0, stream>>>(
        x, qkv_w, nullptr, Qb, TOKENS, 0, CDIM, 0);
    // K,V gathered = x[gather] @ qkv_w[768:2304].T
    gemm_k768<<<dim3((BATCH * MG + 63) / 64, 1536 / 64), blk, 0, stream>>>(
        x, qkv_w, nullptr, KVb, BATCH * MG, CDIM, 1536, 1);
    // fused masked attention
    attn_fused<<<dim3(BATCH * NHEAD, (NTOK + 63) / 64), blk, 0, stream>>>(Qb, KVb, AOb);
    // out = AO @ proj_w.T + proj_b
    gemm_k768<<<dim3(TOKENS / 64, CDIM / 64), blk, 0, stream>>>(
        AOb, proj_w, proj_b, out, TOKENS, 0, CDIM, 0);
}

// Round 3
// 234.297 us; speedup vs baseline: 3.5913x; 3.5913x over previous
//
#include <hip/hip_runtime.h>
#include <stdint.h>

#define NORI   197
#define FRAMES 8
#define NTOK   1576
#define BATCH  8
#define NHEAD  12
#define CDIM   768
#define MG     204
#define TOKENS 12608

typedef _Float16 half8 __attribute__((ext_vector_type(8)));
typedef _Float16 half4 __attribute__((ext_vector_type(4)));
typedef float floatx4 __attribute__((ext_vector_type(4)));

typedef const __attribute__((address_space(1))) void GPTR;
typedef __attribute__((address_space(3))) void LPTR;

__device__ __forceinline__ int gather_idx(int m) {
    if (m < 8) return m * NORI;
    int u = m - 8;
    int f, t;
    if (u < 100) { f = u / 25; t = u - f * 25; }
    else         { f = 4 + (u - 100) / 24; t = (u - 100) - (f - 4) * 24; }
    return f * NORI + 1 + f + 8 * t;
}
__device__ __forceinline__ int col_frame(int m) {  // m in [8,204)
    int u = m - 8;
    return (u < 100) ? (u / 25) : (4 + (u - 100) / 24);
}

// ---------------- fp32 -> fp16 cast (8 elems/thread) ----------------
__global__ __launch_bounds__(256) void cast_f32_f16(
    const float* __restrict__ in, _Float16* __restrict__ out, int n8)
{
    int i = blockIdx.x * 256 + threadIdx.x;
    if (i >= n8) return;
    float4 a = ((const float4*)in)[2 * i];
    float4 b = ((const float4*)in)[2 * i + 1];
    half8 o = { (_Float16)a.x, (_Float16)a.y, (_Float16)a.z, (_Float16)a.w,
                (_Float16)b.x, (_Float16)b.y, (_Float16)b.z, (_Float16)b.w };
    ((half8*)out)[i] = o;
}

// ---------------- MFMA GEMM: Y = A @ W[Woff:...]^T (+bias) ----------------
// A: [M x 768] fp16 (optionally gathered rows), W: rows of 768 fp16.
// 128x128 tile, BK=32, 256 thr = 4 waves (2x2 of 64x64), 16x16x32 f16 MFMA.
// XOR chunk swizzle applied on the GLOBAL side of global_load_lds so LDS
// fragment reads are 2-way (free) bank aliased.
__global__ __launch_bounds__(256) void gemm_mfma(
    const _Float16* __restrict__ A, const _Float16* __restrict__ W,
    const float* __restrict__ bias, void* __restrict__ Y,
    int M, int Woff, int ldY, int gather, int out_f32)
{
    __shared__ __align__(16) _Float16 As[128 * 32];
    __shared__ __align__(16) _Float16 Bs[128 * 32];

    const int tid = threadIdx.x;
    const int w = tid >> 6, l = tid & 63;
    const int r0 = blockIdx.x * 128, c0 = blockIdx.y * 128;
    const int wm = (w >> 1) * 64, wn = (w & 1) * 64;

    // staging source pointers: wave w stages tile rows [w*32, w*32+32)
    const _Float16* sa[2];
    const _Float16* sb[2];
    _Float16* ldsa[2];
    _Float16* ldsb[2];
#pragma unroll
    for (int i = 0; i < 2; i++) {
        int rt = w * 32 + i * 16 + (l >> 2);
        int cg = (l & 3) ^ ((l >> 3) & 3);       // swizzled global chunk
        int ra = min(r0 + rt, M - 1);
        if (gather) { int b = ra / MG; int m = ra - b * MG; ra = b * NTOK + gather_idx(m); }
        sa[i] = A + (size_t)ra * CDIM + cg * 8;
        sb[i] = W + (size_t)(Woff + c0 + rt) * CDIM + cg * 8;
        ldsa[i] = &As[(w * 32 + i * 16) * 32];
        ldsb[i] = &Bs[(w * 32 + i * 16) * 32];
    }

    floatx4 acc[4][4] = {};
    const int fc = ((l >> 4) ^ ((l >> 1) & 3)) * 8;   // fragment chunk (halfs)
    const int mrow = l & 15;

    for (int kb = 0; kb < CDIM; kb += 32) {
        __syncthreads();
#pragma unroll
        for (int i = 0; i < 2; i++) {
            __builtin_amdgcn_global_load_lds((GPTR*)(sa[i] + kb), (LPTR*)ldsa[i], 16, 0, 0);
            __builtin_amdgcn_global_load_lds((GPTR*)(sb[i] + kb), (LPTR*)ldsb[i], 16, 0, 0);
        }
        __syncthreads();

        half8 af[4], bf[4];
#pragma unroll
        for (int t = 0; t < 4; t++) {
            af[t] = *(const half8*)&As[(wm + t * 16 + mrow) * 32 + fc];
            bf[t] = *(const half8*)&Bs[(wn + t * 16 + mrow) * 32 + fc];
        }
#pragma unroll
        for (int mt = 0; mt < 4; mt++)
#pragma unroll
            for (int nt = 0; nt < 4; nt++)
                acc[mt][nt] = __builtin_amdgcn_mfma_f32_16x16x32_f16(af[mt], bf[nt], acc[mt][nt], 0, 0, 0);
    }

    // epilogue: D row = (l>>4)*4 + r, col = l&15 (per 16x16 tile)
#pragma unroll
    for (int nt = 0; nt < 4; nt++) {
        int col = c0 + wn + nt * 16 + (l & 15);
        float bv = bias ? bias[col] : 0.f;
#pragma unroll
        for (int mt = 0; mt < 4; mt++) {
#pragma unroll
            for (int r = 0; r < 4; r++) {
                int row = r0 + wm + mt * 16 + (l >> 4) * 4 + r;
                if (row < M) {
                    if (out_f32) ((float*)Y)[(size_t)row * ldY + col] = acc[mt][nt][r] + bv;
                    else ((_Float16*)Y)[(size_t)row * ldY + col] = (_Float16)acc[mt][nt][r];
                }
            }
        }
    }
}

// ---------------- fused masked attention, MFMA ----------------
// block = (b,h) x 64 q-rows. K LDS [208 x 72], Vt LDS [64 x 216],
// P reuses K's buffer as [64 x 216]. 4 waves x 16 q-rows each.
__global__ __launch_bounds__(256) void attn_mfma(
    const _Float16* __restrict__ Qh, const _Float16* __restrict__ KVh,
    _Float16* __restrict__ AOh)
{
    __shared__ __align__(16) _Float16 KP[208 * 72];   // K then P
    __shared__ __align__(16) _Float16 Vt[64 * 216];

    const int tid = threadIdx.x;
    const int bh = blockIdx.x;
    const int b = bh / NHEAD, h = bh - b * NHEAD;
    const int qb0 = blockIdx.y * 64;

    // ---- stage K [208x72] (rows >=204 zero) and Vt [64x216] transposed ----
    for (int e = tid; e < 208 * 8; e += 256) {      // 16B chunks of K
        int row = e >> 3, c8 = (e & 7) * 8;
        half8 v = {};
        if (row < MG) v = *(const half8*)&KVh[(size_t)(b * MG + row) * 1536 + h * 64 + c8];
        *(half8*)&KP[row * 72 + c8] = v;
    }
    for (int e = tid; e < 208 * 8; e += 256) {      // V chunks, transposed store
        int mp = e >> 3, d0 = (e & 7) * 8;
        half8 v = {};
        if (mp < MG) v = *(const half8*)&KVh[(size_t)(b * MG + mp) * 1536 + 768 + h * 64 + d0];
#pragma unroll
        for (int j = 0; j < 8; j++) Vt[(d0 + j) * 216 + mp] = v[j];
    }
    __syncthreads();

    const int w = tid >> 6, l = tid & 63;
    const int lm = l & 15, lq = l >> 4;

    // column frame per n-tile (col = t*16 + lm): -1 cls (always 1.0), -2 invalid
    int cf[13];
#pragma unroll
    for (int t = 0; t < 13; t++) {
        int col = t * 16 + lm;
        cf[t] = (col < 8) ? -1 : (col >= MG ? -2 : col_frame(col));
    }

    // ---- QK^T: wave's 16 q-rows vs 208 cols ----
    floatx4 acc[13] = {};
    const int qrowA = min(qb0 + w * 16 + lm, NTOK - 1);
    const _Float16* qbase = Qh + (size_t)(b * NTOK + qrowA) * CDIM + h * 64;
#pragma unroll
    for (int ks = 0; ks < 64; ks += 32) {
        half8 aq = *(const half8*)(qbase + ks + lq * 8);
#pragma unroll
        for (int t = 0; t < 13; t++) {
            half8 bk = *(const half8*)&KP[(t * 16 + lm) * 72 + ks + lq * 8];
            acc[t] = __builtin_amdgcn_mfma_f32_16x16x32_f16(aq, bk, acc[t], 0, 0, 0);
        }
    }

    // ---- masked softmax per row (rows m = lq*4+r) ----
#pragma unroll
    for (int r = 0; r < 4; r++) {
        int qrow = qb0 + w * 16 + lq * 4 + r;
        int rf = min(qrow, NTOK - 1) / NORI;
        float sv[13];
        float mx = -1e30f;
#pragma unroll
        for (int t = 0; t < 13; t++) {
            float s = acc[t][r] * 0.125f;
            s *= (cf[t] == -1 || cf[t] == rf) ? 1.f : 0.8f;
            if (cf[t] == -2) s = -1e30f;
            sv[t] = s;
            mx = fmaxf(mx, s);
        }
#pragma unroll
        for (int off = 1; off < 16; off <<= 1) mx = fmaxf(mx, __shfl_xor(mx, off, 64));
        float sum = 0.f;
#pragma unroll
        for (int t = 0; t < 13; t++) { sv[t] = __expf(sv[t] - mx); sum += sv[t]; }
#pragma unroll
        for (int off = 1; off < 16; off <<= 1) sum += __shfl_xor(sum, off, 64);
        float inv = 1.f / sum;
#pragma unroll
        for (int t = 0; t < 13; t++) acc[t][r] = sv[t] * inv;   // stash P
    }

    __syncthreads();   // all waves done reading K before P overwrites it
    _Float16* P = KP;  // [64 x 216]
#pragma unroll
    for (int t = 0; t < 13; t++)
#pragma unroll
        for (int r = 0; r < 4; r++)
            P[(w * 16 + lq * 4 + r) * 216 + t * 16 + lm] = (_Float16)acc[t][r];
    __syncthreads();

    // ---- PV: O[16 x 64] per wave, k over 208 ----
    floatx4 oacc[4] = {};
    const _Float16* prow = &P[(w * 16 + lm) * 216];
#pragma unroll
    for (int ks = 0; ks < 192; ks += 32) {
        half8 ap = *(const half8*)(prow + ks + lq * 8);
#pragma unroll
        for (int t = 0; t < 4; t++) {
            half8 bv = *(const half8*)&Vt[(t * 16 + lm) * 216 + ks + lq * 8];
            oacc[t] = __builtin_amdgcn_mfma_f32_16x16x32_f16(ap, bv, oacc[t], 0, 0, 0);
        }
    }
    {   // K=16 tail (cols 192..207) — legacy intrinsic name has no underscore
        half4 ap4 = *(const half4*)(prow + 192 + lq * 4);
#pragma unroll
        for (int t = 0; t < 4; t++) {
            half4 bv4 = *(const half4*)&Vt[(t * 16 + lm) * 216 + 192 + lq * 4];
            oacc[t] = __builtin_amdgcn_mfma_f32_16x16x16f16(ap4, bv4, oacc[t], 0, 0, 0);
        }
    }

#pragma unroll
    for (int t = 0; t < 4; t++)
#pragma unroll
        for (int r = 0; r < 4; r++) {
            int qrow = qb0 + w * 16 + lq * 4 + r;
            if (qrow < NTOK)
                AOh[(size_t)(b * NTOK + qrow) * CDIM + h * 64 + t * 16 + lm] = (_Float16)oacc[t][r];
        }
}

extern "C" void kernel_launch(void* const* d_in, const int* in_sizes, int n_in,
                              void* d_out, int out_size, void* d_ws, size_t ws_size,
                              hipStream_t stream) {
    const float* x      = (const float*)d_in[0];
    const float* qkv_w  = (const float*)d_in[1];
    const float* proj_w = (const float*)d_in[2];
    const float* proj_b = (const float*)d_in[3];
    float* out = (float*)d_out;

    _Float16* xh    = (_Float16*)d_ws;                       // 9,682,944
    _Float16* qkvwh = xh + (size_t)TOKENS * CDIM;            // 1,769,472
    _Float16* projwh = qkvwh + (size_t)3 * CDIM * CDIM;      //   589,824
    _Float16* Qh    = projwh + (size_t)CDIM * CDIM;          // 9,682,944
    _Float16* KVh   = Qh + (size_t)TOKENS * CDIM;            // 2,506,752
    _Float16* AOh   = KVh + (size_t)(BATCH * MG) * 1536;     // 9,682,944

    dim3 blk(256);
    cast_f32_f16<<<dim3((TOKENS * CDIM / 8 + 255) / 256), blk, 0, stream>>>(x, xh, TOKENS * CDIM / 8);
    cast_f32_f16<<<dim3((3 * CDIM * CDIM / 8 + 255) / 256), blk, 0, stream>>>(qkv_w, qkvwh, 3 * CDIM * CDIM / 8);
    cast_f32_f16<<<dim3((CDIM * CDIM / 8 + 255) / 256), blk, 0, stream>>>(proj_w, projwh, CDIM * CDIM / 8);

    // Q = x @ qkv_w[0:768]^T   (fp16 out)
    gemm_mfma<<<dim3((TOKENS + 127) / 128, CDIM / 128), blk, 0, stream>>>(
        xh, qkvwh, nullptr, Qh, TOKENS, 0, CDIM, 0, 0);
    // KV(gathered) = x[idx] @ qkv_w[768:2304]^T   (fp16 out)
    gemm_mfma<<<dim3((BATCH * MG + 127) / 128, 1536 / 128), blk, 0, stream>>>(
        xh, qkvwh, nullptr, KVh, BATCH * MG, CDIM, 1536, 1, 0);
    // fused attention
    attn_mfma<<<dim3(BATCH * NHEAD, (NTOK + 63) / 64), blk, 0, stream>>>(Qh, KVh, AOh);
    // out = AO @ proj_w^T + b   (fp32 out)
    gemm_mfma<<<dim3((TOKENS + 127) / 128, CDIM / 128), blk, 0, stream>>>(
        AOh, projwh, proj_b, out, TOKENS, 0, CDIM, 0, 1);
}

// Round 4
// 217.698 us; speedup vs baseline: 3.8651x; 1.0762x over previous
//
#include <hip/hip_runtime.h>
#include <stdint.h>

#define NORI   197
#define FRAMES 8
#define NTOK   1576
#define BATCH  8
#define NHEAD  12
#define CDIM   768
#define MG     204
#define TOKENS 12608

typedef _Float16 half8 __attribute__((ext_vector_type(8)));
typedef float floatx4 __attribute__((ext_vector_type(4)));

typedef const __attribute__((address_space(1))) void GPTR;
typedef __attribute__((address_space(3))) void LPTR;

__device__ __forceinline__ int gather_idx(int m) {
    if (m < 8) return m * NORI;
    int u = m - 8;
    int f, t;
    if (u < 100) { f = u / 25; t = u - f * 25; }
    else         { f = 4 + (u - 100) / 24; t = (u - 100) - (f - 4) * 24; }
    return f * NORI + 1 + f + 8 * t;
}
__device__ __forceinline__ int col_frame(int m) {  // m in [8,204)
    int u = m - 8;
    return (u < 100) ? (u / 25) : (4 + (u - 100) / 24);
}

// ---------------- fused fp32 -> fp16 cast of x, qkv_w, proj_w ----------------
// destinations are contiguous in ws (xh | qkvwh | projwh)
__global__ __launch_bounds__(256) void cast_all(
    const float* __restrict__ x, const float* __restrict__ qkvw,
    const float* __restrict__ projw, _Float16* __restrict__ out)
{
    const int n1 = TOKENS * CDIM / 8, n2 = 3 * CDIM * CDIM / 8, n3 = CDIM * CDIM / 8;
    int i = blockIdx.x * 256 + threadIdx.x;
    if (i >= n1 + n2 + n3) return;
    const float* src; int off;
    if (i < n1)           { src = x;     off = i; }
    else if (i < n1 + n2) { src = qkvw;  off = i - n1; }
    else                  { src = projw; off = i - n1 - n2; }
    float4 a = ((const float4*)src)[2 * off];
    float4 b = ((const float4*)src)[2 * off + 1];
    half8 o = { (_Float16)a.x, (_Float16)a.y, (_Float16)a.z, (_Float16)a.w,
                (_Float16)b.x, (_Float16)b.y, (_Float16)b.z, (_Float16)b.w };
    ((half8*)out)[i] = o;
}

// ---------------- MFMA GEMM body: Y[r,c] = A[row(r),:] . W[Woff+c,:] ----------------
// 128x128 tile, BK=32, 4 waves (2x2 of 64x64), 16x16x32 f16 MFMA,
// global-side XOR chunk swizzle + global_load_lds width 16.
template <int OUT_F32>
__device__ __forceinline__ void gemm_body(
    const _Float16* __restrict__ A, const _Float16* __restrict__ W,
    const float* __restrict__ bias, void* __restrict__ Y,
    int M, int Woff, int ldY, int gather, int r0, int c0,
    _Float16* As, _Float16* Bs)
{
    const int tid = threadIdx.x;
    const int w = tid >> 6, l = tid & 63;
    const int wm = (w >> 1) * 64, wn = (w & 1) * 64;

    const _Float16* sa[2];
    const _Float16* sb[2];
    _Float16* ldsa[2];
    _Float16* ldsb[2];
#pragma unroll
    for (int i = 0; i < 2; i++) {
        int rt = w * 32 + i * 16 + (l >> 2);
        int cg = (l & 3) ^ ((l >> 3) & 3);       // swizzled global chunk
        int ra = min(r0 + rt, M - 1);
        if (gather) { int b = ra / MG; int m = ra - b * MG; ra = b * NTOK + gather_idx(m); }
        sa[i] = A + (size_t)ra * CDIM + cg * 8;
        sb[i] = W + (size_t)(Woff + c0 + rt) * CDIM + cg * 8;
        ldsa[i] = &As[(w * 32 + i * 16) * 32];
        ldsb[i] = &Bs[(w * 32 + i * 16) * 32];
    }

    floatx4 acc[4][4] = {};
    const int fc = ((l >> 4) ^ ((l >> 1) & 3)) * 8;
    const int mrow = l & 15;

    for (int kb = 0; kb < CDIM; kb += 32) {
        __syncthreads();
#pragma unroll
        for (int i = 0; i < 2; i++) {
            __builtin_amdgcn_global_load_lds((GPTR*)(sa[i] + kb), (LPTR*)ldsa[i], 16, 0, 0);
            __builtin_amdgcn_global_load_lds((GPTR*)(sb[i] + kb), (LPTR*)ldsb[i], 16, 0, 0);
        }
        __syncthreads();

        half8 af[4], bf[4];
#pragma unroll
        for (int t = 0; t < 4; t++) {
            af[t] = *(const half8*)&As[(wm + t * 16 + mrow) * 32 + fc];
            bf[t] = *(const half8*)&Bs[(wn + t * 16 + mrow) * 32 + fc];
        }
#pragma unroll
        for (int mt = 0; mt < 4; mt++)
#pragma unroll
            for (int nt = 0; nt < 4; nt++)
                acc[mt][nt] = __builtin_amdgcn_mfma_f32_16x16x32_f16(af[mt], bf[nt], acc[mt][nt], 0, 0, 0);
    }

#pragma unroll
    for (int nt = 0; nt < 4; nt++) {
        int col = c0 + wn + nt * 16 + (l & 15);
        float bv = bias ? bias[col] : 0.f;
#pragma unroll
        for (int mt = 0; mt < 4; mt++) {
#pragma unroll
            for (int r = 0; r < 4; r++) {
                int row = r0 + wm + mt * 16 + (l >> 4) * 4 + r;
                if (row < M) {
                    if (OUT_F32) ((float*)Y)[(size_t)row * ldY + col] = acc[mt][nt][r] + bv;
                    else ((_Float16*)Y)[(size_t)row * ldY + col] = (_Float16)acc[mt][nt][r];
                }
            }
        }
    }
}

// Q GEMM (594 blocks) + gathered-KV GEMM (156 blocks) in one dispatch
__global__ __launch_bounds__(256) void gemm_qkv(
    const _Float16* __restrict__ xh, const _Float16* __restrict__ qkvwh,
    _Float16* __restrict__ Qh, _Float16* __restrict__ KVh)
{
    __shared__ __align__(16) _Float16 As[128 * 32];
    __shared__ __align__(16) _Float16 Bs[128 * 32];
    int bx = blockIdx.x;
    if (bx < 594) {
        gemm_body<0>(xh, qkvwh, nullptr, Qh, TOKENS, 0, CDIM, 0,
                     (bx / 6) * 128, (bx % 6) * 128, As, Bs);
    } else {
        int b2 = bx - 594;
        gemm_body<0>(xh, qkvwh, nullptr, KVh, BATCH * MG, CDIM, 1536, 1,
                     (b2 / 12) * 128, (b2 % 12) * 128, As, Bs);
    }
}

__global__ __launch_bounds__(256) void gemm_proj(
    const _Float16* __restrict__ AOh, const _Float16* __restrict__ projwh,
    const float* __restrict__ bias, float* __restrict__ out)
{
    __shared__ __align__(16) _Float16 As[128 * 32];
    __shared__ __align__(16) _Float16 Bs[128 * 32];
    int bx = blockIdx.x;
    gemm_body<1>(AOh, projwh, bias, out, TOKENS, 0, CDIM, 0,
                 (bx / 6) * 128, (bx % 6) * 128, As, Bs);
}

// ---------------- fused masked attention, MFMA ----------------
// block = (b,h) x 320 q-rows (5 row-tiles of 16 per wave). K/V staged ONCE.
// No barriers in the tile loop: P rows are per-wave-owned.
__global__ __launch_bounds__(256) void attn_mfma(
    const _Float16* __restrict__ Qh, const _Float16* __restrict__ KVh,
    _Float16* __restrict__ AOh)
{
    __shared__ __align__(16) _Float16 Ks[208 * 72];
    __shared__ __align__(16) _Float16 Vt[64 * 216];
    __shared__ __align__(16) _Float16 Ps[64 * 216];   // wave w owns rows [w*16, w*16+16)

    const int tid = threadIdx.x;
    const int bh = blockIdx.x;
    const int b = bh / NHEAD, h = bh - b * NHEAD;
    const int qc0 = blockIdx.y * 320;

    // ---- stage K [208x72] (rows >= 204 zero) ----
    for (int e = tid; e < 208 * 8; e += 256) {
        int row = e >> 3, c8 = (e & 7) * 8;
        half8 v = {};
        if (row < MG) v = *(const half8*)&KVh[(size_t)(b * MG + row) * 1536 + h * 64 + c8];
        *(half8*)&Ks[row * 72 + c8] = v;
    }
    // ---- stage Vt [64x216] transposed; lane map: d-chunk = tid>>5, m = tid&31 ----
    {
        const int d0 = (tid >> 5) * 8, lmp = tid & 31;
#pragma unroll
        for (int mo = 0; mo < 7; mo++) {
            int mp = mo * 32 + lmp;
            if (mp >= 208) continue;
            half8 v = {};
            if (mp < MG) v = *(const half8*)&KVh[(size_t)(b * MG + mp) * 1536 + 768 + h * 64 + d0];
#pragma unroll
            for (int j = 0; j < 8; j++) Vt[(d0 + j) * 216 + mp] = v[j];
        }
    }
    __syncthreads();

    const int w = tid >> 6, l = tid & 63;
    const int lm = l & 15, lq = l >> 4;

    int cf[13];
#pragma unroll
    for (int t = 0; t < 13; t++) {
        int col = t * 16 + lm;
        cf[t] = (col < 8) ? -1 : (col >= MG ? -2 : col_frame(col));
    }

    _Float16* Pw = &Ps[(w * 16) * 216];

    for (int t5 = 0; t5 < 5; t5++) {
        const int rb = qc0 + t5 * 64 + w * 16;
        if (rb >= NTOK) break;   // no barriers below — safe per-wave exit

        // ---- QK^T: 16 q-rows vs 208 cols ----
        floatx4 acc[13] = {};
        const int qrowA = min(rb + lm, NTOK - 1);
        const _Float16* qbase = Qh + (size_t)(b * NTOK + qrowA) * CDIM + h * 64;
#pragma unroll
        for (int ks = 0; ks < 64; ks += 32) {
            half8 aq = *(const half8*)(qbase + ks + lq * 8);
#pragma unroll
            for (int t = 0; t < 13; t++) {
                half8 bk = *(const half8*)&Ks[(t * 16 + lm) * 72 + ks + lq * 8];
                acc[t] = __builtin_amdgcn_mfma_f32_16x16x32_f16(aq, bk, acc[t], 0, 0, 0);
            }
        }

        // ---- masked softmax (rows lq*4 + r) ----
#pragma unroll
        for (int r = 0; r < 4; r++) {
            int qrow = min(rb + lq * 4 + r, NTOK - 1);
            int rf = qrow / NORI;
            float sv[13];
            float mx = -1e30f;
#pragma unroll
            for (int t = 0; t < 13; t++) {
                float s = acc[t][r] * 0.125f;
                s *= (cf[t] == -1 || cf[t] == rf) ? 1.f : 0.8f;
                if (cf[t] == -2) s = -1e30f;
                sv[t] = s;
                mx = fmaxf(mx, s);
            }
#pragma unroll
            for (int off = 1; off < 16; off <<= 1) mx = fmaxf(mx, __shfl_xor(mx, off, 64));
            float sum = 0.f;
#pragma unroll
            for (int t = 0; t < 13; t++) { sv[t] = __expf(sv[t] - mx); sum += sv[t]; }
#pragma unroll
            for (int off = 1; off < 16; off <<= 1) sum += __shfl_xor(sum, off, 64);
            float inv = 1.f / sum;
#pragma unroll
            for (int t = 0; t < 13; t++) acc[t][r] = sv[t] * inv;
        }

        // ---- P to per-wave LDS rows (no cross-wave sharing -> no barrier) ----
#pragma unroll
        for (int t = 0; t < 13; t++)
#pragma unroll
            for (int r = 0; r < 4; r++)
                Pw[(lq * 4 + r) * 216 + t * 16 + lm] = (_Float16)acc[t][r];

        // ---- PV: O[16 x 64], k over 208 (cols 204..207 have P=0, Vt=0) ----
        floatx4 oacc[4] = {};
        const _Float16* prow = &Pw[lm * 216];
#pragma unroll
        for (int ks = 0; ks < 192; ks += 32) {
            half8 ap = *(const half8*)(prow + ks + lq * 8);
#pragma unroll
            for (int t = 0; t < 4; t++) {
                half8 bv = *(const half8*)&Vt[(t * 16 + lm) * 216 + ks + lq * 8];
                oacc[t] = __builtin_amdgcn_mfma_f32_16x16x32_f16(ap, bv, oacc[t], 0, 0, 0);
            }
        }
        {   // K=16 tail (cols 192..207)
            typedef _Float16 half4v __attribute__((ext_vector_type(4)));
            half4v ap4 = *(const half4v*)(prow + 192 + lq * 4);
#pragma unroll
            for (int t = 0; t < 4; t++) {
                half4v bv4 = *(const half4v*)&Vt[(t * 16 + lm) * 216 + 192 + lq * 4];
                oacc[t] = __builtin_amdgcn_mfma_f32_16x16x16f16(ap4, bv4, oacc[t], 0, 0, 0);
            }
        }

#pragma unroll
        for (int t = 0; t < 4; t++)
#pragma unroll
            for (int r = 0; r < 4; r++) {
                int qrow = rb + lq * 4 + r;
                if (qrow < NTOK)
                    AOh[(size_t)(b * NTOK + qrow) * CDIM + h * 64 + t * 16 + lm] = (_Float16)oacc[t][r];
            }
    }
}

extern "C" void kernel_launch(void* const* d_in, const int* in_sizes, int n_in,
                              void* d_out, int out_size, void* d_ws, size_t ws_size,
                              hipStream_t stream) {
    const float* x      = (const float*)d_in[0];
    const float* qkv_w  = (const float*)d_in[1];
    const float* proj_w = (const float*)d_in[2];
    const float* proj_b = (const float*)d_in[3];
    float* out = (float*)d_out;

    _Float16* xh     = (_Float16*)d_ws;                      // 9,682,944
    _Float16* qkvwh  = xh + (size_t)TOKENS * CDIM;           // 1,769,472
    _Float16* projwh = qkvwh + (size_t)3 * CDIM * CDIM;      //   589,824
    _Float16* Qh     = projwh + (size_t)CDIM * CDIM;         // 9,682,944
    _Float16* KVh    = Qh + (size_t)TOKENS * CDIM;           // 2,506,752
    _Float16* AOh    = KVh + (size_t)(BATCH * MG) * 1536;    // 9,682,944

    dim3 blk(256);
    const int ncast = (TOKENS * CDIM + 3 * CDIM * CDIM + CDIM * CDIM) / 8;
    cast_all<<<dim3((ncast + 255) / 256), blk, 0, stream>>>(x, qkv_w, proj_w, xh);

    gemm_qkv<<<dim3(594 + 156), blk, 0, stream>>>(xh, qkvwh, Qh, KVh);

    attn_mfma<<<dim3(BATCH * NHEAD, 5), blk, 0, stream>>>(Qh, KVh, AOh);

    gemm_proj<<<dim3(594), blk, 0, stream>>>(AOh, projwh, proj_b, out);
}

// Round 5
// 200.333 us; speedup vs baseline: 4.2002x; 1.0867x over previous
//
#include <hip/hip_runtime.h>
#include <stdint.h>

#define NORI   197
#define FRAMES 8
#define NTOK   1576
#define BATCH  8
#define NHEAD  12
#define CDIM   768
#define MG     204
#define TOKENS 12608

typedef _Float16 half8 __attribute__((ext_vector_type(8)));
typedef float floatx4 __attribute__((ext_vector_type(4)));

typedef const __attribute__((address_space(1))) void GPTR;
typedef __attribute__((address_space(3))) void LPTR;

__device__ __forceinline__ int gather_idx(int m) {
    if (m < 8) return m * NORI;
    int u = m - 8;
    int f, t;
    if (u < 100) { f = u / 25; t = u - f * 25; }
    else         { f = 4 + (u - 100) / 24; t = (u - 100) - (f - 4) * 24; }
    return f * NORI + 1 + f + 8 * t;
}
__device__ __forceinline__ int col_frame(int m) {  // m in [8,204)
    int u = m - 8;
    return (u < 100) ? (u / 25) : (4 + (u - 100) / 24);
}

// ---------------- fused fp32 -> fp16 cast of x, qkv_w, proj_w ----------------
__global__ __launch_bounds__(256) void cast_all(
    const float* __restrict__ x, const float* __restrict__ qkvw,
    const float* __restrict__ projw, _Float16* __restrict__ out)
{
    const int n1 = TOKENS * CDIM / 8, n2 = 3 * CDIM * CDIM / 8, n3 = CDIM * CDIM / 8;
    int i = blockIdx.x * 256 + threadIdx.x;
    if (i >= n1 + n2 + n3) return;
    const float* src; int off;
    if (i < n1)           { src = x;     off = i; }
    else if (i < n1 + n2) { src = qkvw;  off = i - n1; }
    else                  { src = projw; off = i - n1 - n2; }
    float4 a = ((const float4*)src)[2 * off];
    float4 b = ((const float4*)src)[2 * off + 1];
    half8 o = { (_Float16)a.x, (_Float16)a.y, (_Float16)a.z, (_Float16)a.w,
                (_Float16)b.x, (_Float16)b.y, (_Float16)b.z, (_Float16)b.w };
    ((half8*)out)[i] = o;
}

// ---------------- MFMA GEMM body: Y[r,c] = A[row(r),:] . W[Woff+c,:] ----------------
template <int OUT_F32>
__device__ __forceinline__ void gemm_body(
    const _Float16* __restrict__ A, const _Float16* __restrict__ W,
    const float* __restrict__ bias, void* __restrict__ Y,
    int M, int Woff, int ldY, int gather, int r0, int c0,
    _Float16* As, _Float16* Bs)
{
    const int tid = threadIdx.x;
    const int w = tid >> 6, l = tid & 63;
    const int wm = (w >> 1) * 64, wn = (w & 1) * 64;

    const _Float16* sa[2];
    const _Float16* sb[2];
    _Float16* ldsa[2];
    _Float16* ldsb[2];
#pragma unroll
    for (int i = 0; i < 2; i++) {
        int rt = w * 32 + i * 16 + (l >> 2);
        int cg = (l & 3) ^ ((l >> 3) & 3);       // swizzled global chunk
        int ra = min(r0 + rt, M - 1);
        if (gather) { int b = ra / MG; int m = ra - b * MG; ra = b * NTOK + gather_idx(m); }
        sa[i] = A + (size_t)ra * CDIM + cg * 8;
        sb[i] = W + (size_t)(Woff + c0 + rt) * CDIM + cg * 8;
        ldsa[i] = &As[(w * 32 + i * 16) * 32];
        ldsb[i] = &Bs[(w * 32 + i * 16) * 32];
    }

    floatx4 acc[4][4] = {};
    const int fc = ((l >> 4) ^ ((l >> 1) & 3)) * 8;
    const int mrow = l & 15;

    for (int kb = 0; kb < CDIM; kb += 32) {
        __syncthreads();
#pragma unroll
        for (int i = 0; i < 2; i++) {
            __builtin_amdgcn_global_load_lds((GPTR*)(sa[i] + kb), (LPTR*)ldsa[i], 16, 0, 0);
            __builtin_amdgcn_global_load_lds((GPTR*)(sb[i] + kb), (LPTR*)ldsb[i], 16, 0, 0);
        }
        __syncthreads();

        half8 af[4], bf[4];
#pragma unroll
        for (int t = 0; t < 4; t++) {
            af[t] = *(const half8*)&As[(wm + t * 16 + mrow) * 32 + fc];
            bf[t] = *(const half8*)&Bs[(wn + t * 16 + mrow) * 32 + fc];
        }
#pragma unroll
        for (int mt = 0; mt < 4; mt++)
#pragma unroll
            for (int nt = 0; nt < 4; nt++)
                acc[mt][nt] = __builtin_amdgcn_mfma_f32_16x16x32_f16(af[mt], bf[nt], acc[mt][nt], 0, 0, 0);
    }

#pragma unroll
    for (int nt = 0; nt < 4; nt++) {
        int col = c0 + wn + nt * 16 + (l & 15);
        float bv = bias ? bias[col] : 0.f;
#pragma unroll
        for (int mt = 0; mt < 4; mt++) {
#pragma unroll
            for (int r = 0; r < 4; r++) {
                int row = r0 + wm + mt * 16 + (l >> 4) * 4 + r;
                if (row < M) {
                    if (OUT_F32) ((float*)Y)[(size_t)row * ldY + col] = acc[mt][nt][r] + bv;
                    else ((_Float16*)Y)[(size_t)row * ldY + col] = (_Float16)acc[mt][nt][r];
                }
            }
        }
    }
}

// Q GEMM (594 blocks) + gathered-KV GEMM (156 blocks) in one dispatch
__global__ __launch_bounds__(256) void gemm_qkv(
    const _Float16* __restrict__ xh, const _Float16* __restrict__ qkvwh,
    _Float16* __restrict__ Qh, _Float16* __restrict__ KVh)
{
    __shared__ __align__(16) _Float16 As[128 * 32];
    __shared__ __align__(16) _Float16 Bs[128 * 32];
    int bx = blockIdx.x;
    if (bx < 594) {
        gemm_body<0>(xh, qkvwh, nullptr, Qh, TOKENS, 0, CDIM, 0,
                     (bx / 6) * 128, (bx % 6) * 128, As, Bs);
    } else {
        int b2 = bx - 594;
        gemm_body<0>(xh, qkvwh, nullptr, KVh, BATCH * MG, CDIM, 1536, 1,
                     (b2 / 12) * 128, (b2 % 12) * 128, As, Bs);
    }
}

__global__ __launch_bounds__(256) void gemm_proj(
    const _Float16* __restrict__ AOh, const _Float16* __restrict__ projwh,
    const float* __restrict__ bias, float* __restrict__ out)
{
    __shared__ __align__(16) _Float16 As[128 * 32];
    __shared__ __align__(16) _Float16 Bs[128 * 32];
    int bx = blockIdx.x;
    gemm_body<1>(AOh, projwh, bias, out, TOKENS, 0, CDIM, 0,
                 (bx / 6) * 128, (bx % 6) * 128, As, Bs);
}

// ---------------- fused masked attention, MFMA ----------------
// block = (b,h) x 320 q-rows (5 row-tiles of 16 per wave). K/V staged ONCE.
// LDS = 26112 (Ks, swizzled stride-64) + 26624 (Vt, stride 208) + 27648 (Ps)
//     = 80384 B <= 81920  ->  2 blocks/CU (8 waves), one full dispatch round.
__global__ __launch_bounds__(256, 2) void attn_mfma(
    const _Float16* __restrict__ Qh, const _Float16* __restrict__ KVh,
    _Float16* __restrict__ AOh)
{
    __shared__ __align__(16) _Float16 Ks[204 * 64];  // [row][chunk^(row&7)]
    __shared__ __align__(16) _Float16 Vt[64 * 208];
    __shared__ __align__(16) _Float16 Ps[64 * 216];  // wave w owns rows [w*16, +16)

    const int tid = threadIdx.x;
    const int bh = blockIdx.x;
    const int b = bh / NHEAD, h = bh - b * NHEAD;
    const int qc0 = blockIdx.y * 320;

    // ---- stage K, XOR-swizzled chunks (rows 204..207 unstaged; reads there
    //      land in Vt = finite garbage, fully masked by cf==-2) ----
    for (int e = tid; e < MG * 8; e += 256) {
        int row = e >> 3, c8 = e & 7;
        half8 v = *(const half8*)&KVh[(size_t)(b * MG + row) * 1536 + h * 64 + c8 * 8];
        *(half8*)&Ks[row * 64 + ((c8 ^ (row & 7)) * 8)] = v;
    }
    // ---- stage Vt [64 x 208] transposed ----
    {
        const int d0 = (tid >> 5) * 8, lmp = tid & 31;
#pragma unroll
        for (int mo = 0; mo < 7; mo++) {
            int mp = mo * 32 + lmp;
            if (mp >= 208) continue;
            half8 v = {};
            if (mp < MG) v = *(const half8*)&KVh[(size_t)(b * MG + mp) * 1536 + 768 + h * 64 + d0];
#pragma unroll
            for (int j = 0; j < 8; j++) Vt[(d0 + j) * 208 + mp] = v[j];
        }
    }
    __syncthreads();

    const int w = tid >> 6, l = tid & 63;
    const int lm = l & 15, lq = l >> 4;

    int cf[13];
#pragma unroll
    for (int t = 0; t < 13; t++) {
        int col = t * 16 + lm;
        cf[t] = (col < 8) ? -1 : (col >= MG ? -2 : col_frame(col));
    }

    _Float16* Pw = &Ps[(w * 16) * 216];

    for (int t5 = 0; t5 < 5; t5++) {
        const int rb = qc0 + t5 * 64 + w * 16;
        if (rb >= NTOK) break;   // per-wave exit; no barriers below

        // ---- QK^T: 16 q-rows vs 208 cols ----
        floatx4 acc[13] = {};
        const int qrowA = min(rb + lm, NTOK - 1);
        const _Float16* qbase = Qh + (size_t)(b * NTOK + qrowA) * CDIM + h * 64;
#pragma unroll
        for (int ks = 0; ks < 64; ks += 32) {
            half8 aq = *(const half8*)(qbase + ks + lq * 8);
#pragma unroll
            for (int t = 0; t < 13; t++) {
                half8 bk = *(const half8*)&Ks[(t * 16 + lm) * 64 + (((ks >> 3) + lq) ^ (lm & 7)) * 8];
                acc[t] = __builtin_amdgcn_mfma_f32_16x16x32_f16(aq, bk, acc[t], 0, 0, 0);
            }
        }

        // ---- masked softmax (rows lq*4 + r) ----
#pragma unroll
        for (int r = 0; r < 4; r++) {
            int qrow = min(rb + lq * 4 + r, NTOK - 1);
            int rf = qrow / NORI;
            float sv[13];
            float mx = -1e30f;
#pragma unroll
            for (int t = 0; t < 13; t++) {
                float s = acc[t][r] * 0.125f;
                s *= (cf[t] == -1 || cf[t] == rf) ? 1.f : 0.8f;
                if (cf[t] == -2) s = -1e30f;
                sv[t] = s;
                mx = fmaxf(mx, s);
            }
#pragma unroll
            for (int off = 1; off < 16; off <<= 1) mx = fmaxf(mx, __shfl_xor(mx, off, 64));
            float sum = 0.f;
#pragma unroll
            for (int t = 0; t < 13; t++) { sv[t] = __expf(sv[t] - mx); sum += sv[t]; }
#pragma unroll
            for (int off = 1; off < 16; off <<= 1) sum += __shfl_xor(sum, off, 64);
            float inv = 1.f / sum;
#pragma unroll
            for (int t = 0; t < 13; t++) acc[t][r] = sv[t] * inv;
        }

        // ---- P to per-wave LDS rows ----
#pragma unroll
        for (int t = 0; t < 13; t++)
#pragma unroll
            for (int r = 0; r < 4; r++)
                Pw[(lq * 4 + r) * 216 + t * 16 + lm] = (_Float16)acc[t][r];

        // ---- PV: O[16 x 64], k over 208 (cols 204..207: P=0, Vt=0) ----
        floatx4 oacc[4] = {};
        const _Float16* prow = &Pw[lm * 216];
#pragma unroll
        for (int ks = 0; ks < 192; ks += 32) {
            half8 ap = *(const half8*)(prow + ks + lq * 8);
#pragma unroll
            for (int t = 0; t < 4; t++) {
                half8 bv = *(const half8*)&Vt[(t * 16 + lm) * 208 + ks + lq * 8];
                oacc[t] = __builtin_amdgcn_mfma_f32_16x16x32_f16(ap, bv, oacc[t], 0, 0, 0);
            }
        }
        {   // K=16 tail (cols 192..207)
            typedef _Float16 half4v __attribute__((ext_vector_type(4)));
            half4v ap4 = *(const half4v*)(prow + 192 + lq * 4);
#pragma unroll
            for (int t = 0; t < 4; t++) {
                half4v bv4 = *(const half4v*)&Vt[(t * 16 + lm) * 208 + 192 + lq * 4];
                oacc[t] = __builtin_amdgcn_mfma_f32_16x16x16f16(ap4, bv4, oacc[t], 0, 0, 0);
            }
        }

#pragma unroll
        for (int t = 0; t < 4; t++)
#pragma unroll
            for (int r = 0; r < 4; r++) {
                int qrow = rb + lq * 4 + r;
                if (qrow < NTOK)
                    AOh[(size_t)(b * NTOK + qrow) * CDIM + h * 64 + t * 16 + lm] = (_Float16)oacc[t][r];
            }
    }
}

extern "C" void kernel_launch(void* const* d_in, const int* in_sizes, int n_in,
                              void* d_out, int out_size, void* d_ws, size_t ws_size,
                              hipStream_t stream) {
    const float* x      = (const float*)d_in[0];
    const float* qkv_w  = (const float*)d_in[1];
    const float* proj_w = (const float*)d_in[2];
    const float* proj_b = (const float*)d_in[3];
    float* out = (float*)d_out;

    _Float16* xh     = (_Float16*)d_ws;
    _Float16* qkvwh  = xh + (size_t)TOKENS * CDIM;
    _Float16* projwh = qkvwh + (size_t)3 * CDIM * CDIM;
    _Float16* Qh     = projwh + (size_t)CDIM * CDIM;
    _Float16* KVh    = Qh + (size_t)TOKENS * CDIM;
    _Float16* AOh    = KVh + (size_t)(BATCH * MG) * 1536;

    dim3 blk(256);
    const int ncast = (TOKENS * CDIM + 3 * CDIM * CDIM + CDIM * CDIM) / 8;
    cast_all<<<dim3((ncast + 255) / 256), blk, 0, stream>>>(x, qkv_w, proj_w, xh);

    gemm_qkv<<<dim3(594 + 156), blk, 0, stream>>>(xh, qkvwh, Qh, KVh);

    attn_mfma<<<dim3(BATCH * NHEAD, 5), blk, 0, stream>>>(Qh, KVh, AOh);

    gemm_proj<<<dim3(594), blk, 0, stream>>>(AOh, projwh, proj_b, out);
}